// Round 4
// baseline (428.022 us; speedup 1.0000x reference)
//
#include <hip/hip_runtime.h>
#include <hip/hip_bf16.h>
#include <stdint.h>

#define S_LEN 2048
#define B_SZ  16
#define D_DIM 1024
#define H_DIM 1024
#define M_TOT (S_LEN * B_SZ)      // 32768
#define N_TOT (3 * H_DIM)         // 3072
#define K_TOT D_DIM               // 1024

// ---- GEMM geometry: 256x256 tile, BK=64 (2 ks-halves), 8 waves (2Mx4N) ----
#define BM 256
#define BN 256
#define BK 64
#define NT   (K_TOT / BK)         // 16 K-tiles
#define NTN  (N_TOT / BN)         // 12
#define NWG  ((M_TOT / BM) * NTN) // 1536 (divisible by 8 -> simple XCD swizzle)

#define NCHUNK 32
#define CLEN   64                 // NCHUNK*CLEN == S_LEN
#define NCH    (B_SZ * H_DIM)     // 16384 independent channels

typedef __attribute__((ext_vector_type(8))) short short8;
typedef __attribute__((ext_vector_type(4))) float f32x4;

// ---------- helpers ----------
__device__ __forceinline__ void gload_lds16(const void* g, void* l) {
  __builtin_amdgcn_global_load_lds((__attribute__((address_space(1))) void*)g,
                                   (__attribute__((address_space(3))) void*)l,
                                   16, 0, 0);
}

__device__ __forceinline__ unsigned short f2bfbits(float x) {
  union { __hip_bfloat16 h; unsigned short u; } cv;
  cv.h = __float2bfloat16(x);
  return cv.u;
}

__device__ __forceinline__ float sigmoidf_fast(float y) {
  return 1.f / (1.f + __expf(-y));
}

__device__ __forceinline__ float tanhf_fast(float y) {
  float ay = fabsf(y);
  float e  = __expf(-2.f * ay);
  float t  = (1.f - e) / (1.f + e);
  return copysignf(t, y);
}

// ---------- fp32 -> bf16 conversion (vectorized) ----------
__global__ void cvt_kernel(const float* __restrict__ in,
                           unsigned short* __restrict__ out, int n4) {
  int i = blockIdx.x * 256 + threadIdx.x;
  if (i < n4) {
    float4 v = ((const float4*)in)[i];
    ushort4 o;
    o.x = f2bfbits(v.x); o.y = f2bfbits(v.y);
    o.z = f2bfbits(v.z); o.w = f2bfbits(v.w);
    ((ushort4*)out)[i] = o;
  }
}

// ---------- GEMM: Y = Xb * Wb^T + bias, fused activations ----------
// Quadrant-phase schedule. Tile t+1's 8 prefetch loads issue at q0 of iter t;
// vmcnt(0) at q3 (no-reads phase) + barrier = COLLECTIVE certification before
// any wave reads tile t+1 at iter t+1 q0. ds_reads issue before each phase
// barrier, lgkmcnt(0)+sched_barrier(0) after it (rule #18).
// LDS: A [2 tb][2 ks][256 rows][64 B] at 0; B same at +65536. 128 KiB.
// slot^(row&3) involution swizzle (source-side pre-swizzle + read-side).
__global__ __launch_bounds__(512, 2) void gemm_act(
    const __hip_bfloat16* __restrict__ Xb,
    const __hip_bfloat16* __restrict__ Wb,
    const float* __restrict__ bias,
    unsigned short* __restrict__ wsZ,
    unsigned short* __restrict__ wsF,
    unsigned short* __restrict__ wsO) {
  __shared__ __align__(16) char lds[131072];

  int bid = blockIdx.x;
  int swz = (bid & 7) * (NWG >> 3) + (bid >> 3);   // XCD-aware, bijective
  int tm  = swz / NTN;
  int tn  = swz - tm * NTN;
  const int m0 = tm * BM;
  const int n0 = tn * BN;

  const int tid  = threadIdx.x;
  const int lane = tid & 63;
  const int wid  = tid >> 6;
  const int wr   = wid >> 2;        // 0..1 : wave row  (128 rows each)
  const int wc   = wid & 3;         // 0..3 : wave col  (64 cols each)
  const int lr   = lane & 15;
  const int lg   = lane >> 4;
  const int psl  = (lg ^ (lr & 3)) << 4;   // swizzled 16B slot (read side)

  // staging: thread covers 2x16B per half; row = j*128 + tid/4, slot tid&3
  const int srow  = tid >> 2;               // 0..127
  const int ssl   = ((tid & 3) ^ (srow & 3)) << 4;  // pre-swizzled source slot

  const char* Ab = (const char*)(Xb + (size_t)m0 * K_TOT);
  const char* Bb = (const char*)(Wb + (size_t)n0 * K_TOT);

  f32x4 acc[8][4];
  const f32x4 vz = {0.f, 0.f, 0.f, 0.f};
  #pragma unroll
  for (int m = 0; m < 8; ++m)
    #pragma unroll
    for (int n = 0; n < 4; ++n) acc[m][n] = vz;

  // stage one ks-half of one matrix of tile tt (2 gloads/thread)
  #define STAGE_HALF(gbase, ldsoff, tt, ks)                                   \
    {                                                                         \
      char* l = lds + (ldsoff) + ((((tt) & 1) << 1) | (ks)) * 16384;          \
      const size_t kb = ((size_t)(tt) * 64 + (ks) * 32) * 2;                  \
      _Pragma("unroll")                                                       \
      for (int j = 0; j < 2; ++j) {                                           \
        int r = j * 128 + srow;                                               \
        gload_lds16((gbase) + (size_t)r * (K_TOT * 2) + kb + ssl,             \
                    l + j * 8192 + tid * 16);                                 \
      }                                                                       \
    }

  #define BAR()                                                               \
    { asm volatile("" ::: "memory");                                          \
      __builtin_amdgcn_s_barrier();                                           \
      asm volatile("" ::: "memory"); }

  #define LGKM0()                                                             \
    { asm volatile("s_waitcnt lgkmcnt(0)" ::: "memory");                      \
      __builtin_amdgcn_sched_barrier(0); }

  #define VM0()                                                               \
    { asm volatile("s_waitcnt vmcnt(0)" ::: "memory");                        \
      __builtin_amdgcn_sched_barrier(0); }

  // read A quadrant: 8 frags (4 mm x 2 ks)
  #define READ_A(dst, tb, mh)                                                 \
    _Pragma("unroll")                                                         \
    for (int mm = 0; mm < 4; ++mm)                                            \
      _Pragma("unroll")                                                       \
      for (int ks = 0; ks < 2; ++ks) {                                        \
        int row = wr * 128 + (mh) * 64 + mm * 16 + lr;                        \
        dst[mm][ks] = *(const short8*)(lds + (((tb) << 1) | ks) * 16384 +     \
                                       row * 64 + psl);                       \
      }

  // read B quadrant: 4 frags (2 nn x 2 ks)
  #define READ_B(dst, tb, nh)                                                 \
    _Pragma("unroll")                                                         \
    for (int nn = 0; nn < 2; ++nn)                                            \
      _Pragma("unroll")                                                       \
      for (int ks = 0; ks < 2; ++ks) {                                        \
        int row = wc * 64 + (nh) * 32 + nn * 16 + lr;                         \
        dst[nn][ks] = *(const short8*)(lds + 65536 +                          \
                                       (((tb) << 1) | ks) * 16384 +           \
                                       row * 64 + psl);                       \
      }

  #define MFMA_Q(mh, nh, A, Bf)                                               \
    __builtin_amdgcn_s_setprio(1);                                            \
    _Pragma("unroll")                                                         \
    for (int ks = 0; ks < 2; ++ks)                                            \
      _Pragma("unroll")                                                       \
      for (int mm = 0; mm < 4; ++mm)                                          \
        _Pragma("unroll")                                                     \
        for (int nn = 0; nn < 2; ++nn)                                        \
          acc[(mh) * 4 + mm][(nh) * 2 + nn] =                                 \
              __builtin_amdgcn_mfma_f32_16x16x32_bf16(                        \
                  A[mm][ks], Bf[nn][ks], acc[(mh) * 4 + mm][(nh) * 2 + nn],   \
                  0, 0, 0);                                                   \
    __builtin_amdgcn_s_setprio(0);

  // prologue: stage tile 0 fully, drain, certify
  STAGE_HALF(Ab, 0, 0, 0);
  STAGE_HALF(Ab, 0, 0, 1);
  STAGE_HALF(Bb, 65536, 0, 0);
  STAGE_HALF(Bb, 65536, 0, 1);
  VM0();
  BAR();

  short8 afr[4][2], bfr0[2][2], bfr1[2][2];

  for (int t = 0; t < NT; ++t) {
    const int tb = t & 1;
    // ---- q0: prefetch tile t+1 (8 loads); read A(mh0)+B(nh0) of tile t ----
    if (t + 1 < NT) {
      STAGE_HALF(Ab, 0, t + 1, 0);
      STAGE_HALF(Ab, 0, t + 1, 1);
      STAGE_HALF(Bb, 65536, t + 1, 0);
      STAGE_HALF(Bb, 65536, t + 1, 1);
    }
    READ_A(afr, tb, 0);
    READ_B(bfr0, tb, 0);
    BAR();
    LGKM0();
    MFMA_Q(0, 0, afr, bfr0);
    BAR();
    // ---- q1: read B(nh1); reuse afr ----
    READ_B(bfr1, tb, 1);
    BAR();
    LGKM0();
    MFMA_Q(0, 1, afr, bfr1);
    BAR();
    // ---- q2: read A(mh1); reuse bfr1 ----
    READ_A(afr, tb, 1);
    BAR();
    LGKM0();
    MFMA_Q(1, 1, afr, bfr1);
    BAR();
    // ---- q3: no reads; certify tile t+1 collectively, then MFMA ----
    VM0();
    BAR();
    MFMA_Q(1, 0, afr, bfr0);
    BAR();
  }

  // ---- epilogue: bias + activation -> bf16 -> LDS -> coalesced stores ----
  const int chunk = n0 >> 10;                 // block-uniform (BN=256 | 1024)
  const int hbase = (n0 & (H_DIM - 1)) + wc * 64;
  unsigned short* dst = (chunk == 0) ? wsZ : (chunk == 1) ? wsF : wsO;

  char* ep = lds + wid * 16384;               // 128 rows x 64 cols bf16
  float bv[4];
  #pragma unroll
  for (int n = 0; n < 4; ++n) bv[n] = bias[n0 + wc * 64 + n * 16 + lr];

  #pragma unroll
  for (int m = 0; m < 8; ++m)
    #pragma unroll
    for (int n = 0; n < 4; ++n)
      #pragma unroll
      for (int r = 0; r < 4; ++r) {
        float y = acc[m][n][r] + bv[n];
        float v = (chunk == 0) ? tanhf_fast(y) : sigmoidf_fast(y);
        int rowl = m * 16 + lg * 4 + r;       // 0..127
        *(unsigned short*)(ep + rowl * 128 + ((n * 16 + lr) << 1)) = f2bfbits(v);
      }

  // same-wave LDS readback (compiler inserts lgkmcnt for the alias)
  #pragma unroll
  for (int it = 0; it < 16; ++it) {
    int rl = it * 8 + (lane >> 3);
    short8 v = *(const short8*)(ep + rl * 128 + ((lane & 7) << 4));
    size_t grow = (size_t)(m0 + wr * 128 + rl);
    *(short8*)((char*)dst + (grow * H_DIM + hbase) * 2 + ((lane & 7) << 4)) = v;
  }
}

// ---------- blocked scan pass 1: per-chunk (prod F, acc from 0) ----------
__global__ void scan_pass1(const __hip_bfloat16* __restrict__ F,
                           const __hip_bfloat16* __restrict__ Z,
                           float* __restrict__ chP, float* __restrict__ chA) {
  int t  = blockIdx.x * 256 + threadIdx.x;  // 0 .. NCHUNK*NCH-1
  int ch = t & (NCH - 1);
  int c  = t >> 14;
  size_t base = (size_t)c * CLEN * NCH + ch;
  float P = 1.f, A = 0.f;
  #pragma unroll 8
  for (int i = 0; i < CLEN; ++i) {
    float f = __bfloat162float(F[base + (size_t)i * NCH]);
    float z = __bfloat162float(Z[base + (size_t)i * NCH]);
    A = fmaf(f, A, (1.f - f) * z);
    P *= f;
  }
  chP[t] = P;
  chA[t] = A;
}

// ---------- mid scan: sequential over 32 chunks per channel ----------
__global__ void scan_mid(const float* __restrict__ chP, const float* __restrict__ chA,
                         const float* __restrict__ hidden,
                         float* __restrict__ Cst, float* __restrict__ outLast) {
  int ch = blockIdx.x * 256 + threadIdx.x;  // 0..16383
  float c0 = hidden[ch];
  #pragma unroll
  for (int c = 0; c < NCHUNK; ++c) {
    Cst[c * NCH + ch] = c0;
    c0 = fmaf(chP[c * NCH + ch], c0, chA[c * NCH + ch]);
  }
  outLast[ch] = c0;  // C[S-1] output (fp32)
}

// ---------- pass 2: recompute within chunk with correct start, fuse Hout ----------
__global__ void scan_pass2(const __hip_bfloat16* __restrict__ F,
                           const __hip_bfloat16* __restrict__ Z,
                           const __hip_bfloat16* __restrict__ O,
                           const float* __restrict__ Cst,
                           float* __restrict__ out) {
  int t  = blockIdx.x * 256 + threadIdx.x;
  int ch = t & (NCH - 1);
  int c  = t >> 14;
  float C = Cst[c * NCH + ch];
  size_t base = (size_t)c * CLEN * NCH + ch;
  #pragma unroll 8
  for (int i = 0; i < CLEN; ++i) {
    size_t idx = base + (size_t)i * NCH;
    float f = __bfloat162float(F[idx]);
    float z = __bfloat162float(Z[idx]);
    C = fmaf(f, C, (1.f - f) * z);
    out[idx] = __bfloat162float(O[idx]) * C;
  }
}

extern "C" void kernel_launch(void* const* d_in, const int* in_sizes, int n_in,
                              void* d_out, int out_size, void* d_ws, size_t ws_size,
                              hipStream_t stream) {
  const float* X      = (const float*)d_in[0];  // [S,B,D]
  const float* hidden = (const float*)d_in[1];  // [B,H]
  const float* W      = (const float*)d_in[2];  // [3H,D]
  const float* bias   = (const float*)d_in[3];  // [3H]
  float* out = (float*)d_out;                   // Hout [S,B,H] then C_last [1,B,H]

  char* ws = (char*)d_ws;
  __hip_bfloat16* Xb  = (__hip_bfloat16*)(ws);                 // 67,108,864
  __hip_bfloat16* Wb  = (__hip_bfloat16*)(ws + 67108864);      //  6,291,456
  unsigned short* wsZ = (unsigned short*)(ws + 73400320);      // 67,108,864 (bf16 bits)
  unsigned short* wsF = (unsigned short*)(ws + 140509184);     // 67,108,864
  unsigned short* wsO = (unsigned short*)(ws + 207618048);     // 67,108,864
  float* chP = (float*)(ws + 274726912);                       //  2,097,152
  float* chA = (float*)(ws + 276824064);                       //  2,097,152
  float* Cst = (float*)(ws + 278921216);                       //  2,097,152

  // 1) convert X and W to bf16
  cvt_kernel<<<(M_TOT * K_TOT / 4 + 255) / 256, 256, 0, stream>>>(X, (unsigned short*)Xb, M_TOT * K_TOT / 4);
  cvt_kernel<<<(N_TOT * K_TOT / 4 + 255) / 256, 256, 0, stream>>>(W, (unsigned short*)Wb, N_TOT * K_TOT / 4);

  // 2) fused GEMM + bias + activations (256^2 tile, quadrant phases)
  gemm_act<<<NWG, 512, 0, stream>>>(Xb, Wb, bias, wsZ, wsF, wsO);

  // 3) blocked linear scan
  scan_pass1<<<(NCHUNK * NCH) / 256, 256, 0, stream>>>(
      (const __hip_bfloat16*)wsF, (const __hip_bfloat16*)wsZ, chP, chA);
  scan_mid<<<NCH / 256, 256, 0, stream>>>(chP, chA, hidden, Cst, out + (size_t)M_TOT * H_DIM);
  scan_pass2<<<(NCHUNK * NCH) / 256, 256, 0, stream>>>(
      (const __hip_bfloat16*)wsF, (const __hip_bfloat16*)wsZ,
      (const __hip_bfloat16*)wsO, Cst, out);
}

// Round 5
// 372.954 us; speedup vs baseline: 1.1477x; 1.1477x over previous
//
#include <hip/hip_runtime.h>
#include <hip/hip_bf16.h>
#include <stdint.h>

#define S_LEN 2048
#define B_SZ  16
#define D_DIM 1024
#define H_DIM 1024
#define M_TOT (S_LEN * B_SZ)      // 32768
#define N_TOT (3 * H_DIM)         // 3072
#define K_TOT D_DIM               // 1024

// ---- GEMM geometry: 256x256 tile, BK=64, 8 waves (2Mx4N), 512 threads ----
#define BM 256
#define BN 256
#define BK 64
#define NT   (K_TOT / BK)         // 16 K-tiles
#define NTN  (N_TOT / BN)         // 12
#define NWG  ((M_TOT / BM) * NTN) // 1536 (divisible by 8 -> simple XCD swizzle)

#define NCHUNK 32
#define CLEN   64                 // NCHUNK*CLEN == S_LEN
#define NCH    (B_SZ * H_DIM)     // 16384 independent channels

typedef __attribute__((ext_vector_type(8))) short short8;
typedef __attribute__((ext_vector_type(4))) float f32x4;

// ---------- helpers ----------
__device__ __forceinline__ void gload_lds16(const void* g, void* l) {
  __builtin_amdgcn_global_load_lds((__attribute__((address_space(1))) void*)g,
                                   (__attribute__((address_space(3))) void*)l,
                                   16, 0, 0);
}

__device__ __forceinline__ unsigned short f2bfbits(float x) {
  union { __hip_bfloat16 h; unsigned short u; } cv;
  cv.h = __float2bfloat16(x);
  return cv.u;
}

__device__ __forceinline__ float sigmoidf_fast(float y) {
  return 1.f / (1.f + __expf(-y));
}

__device__ __forceinline__ float tanhf_fast(float y) {
  float ay = fabsf(y);
  float e  = __expf(-2.f * ay);
  float t  = (1.f - e) / (1.f + e);
  return copysignf(t, y);
}

// ---------- fp32 -> bf16 conversion (vectorized) ----------
__global__ void cvt_kernel(const float* __restrict__ in,
                           unsigned short* __restrict__ out, int n4) {
  int i = blockIdx.x * 256 + threadIdx.x;
  if (i < n4) {
    float4 v = ((const float4*)in)[i];
    ushort4 o;
    o.x = f2bfbits(v.x); o.y = f2bfbits(v.y);
    o.z = f2bfbits(v.z); o.w = f2bfbits(v.w);
    ((ushort4*)out)[i] = o;
  }
}

// ---------- GEMM: Y = Xb * Wb^T + bias, fused activations ----------
// 4 quadrant-phases/K-tile; staggered 2-phase-deep prefetch:
//   q0: stage Ah0(t+1)   q1: stage Ah1(t+1)   q2: stage Bh0(t+2)
//   q3: stage Bh1(t+2); vmcnt(4) certifies A(t+1)+B(t+1); barrier.
// LDS: A [2 buf][256 rows][128 B] @0, B same @65536 (128 KiB).
// slot^(row&7) involution swizzle (pre-swizzled global source + read-side):
// 8 slots per 128B row -> conflict-free octets on ds_read_b128.
__global__ __launch_bounds__(512, 2) void gemm_act(
    const __hip_bfloat16* __restrict__ Xb,
    const __hip_bfloat16* __restrict__ Wb,
    const float* __restrict__ bias,
    unsigned short* __restrict__ wsZ,
    unsigned short* __restrict__ wsF,
    unsigned short* __restrict__ wsO) {
  __shared__ __align__(16) char lds[131072];

  int bid = blockIdx.x;
  int swz = (bid & 7) * (NWG >> 3) + (bid >> 3);   // XCD-aware, bijective
  int tm  = swz / NTN;
  int tn  = swz - tm * NTN;
  const int m0 = tm * BM;
  const int n0 = tn * BN;

  const int tid  = threadIdx.x;
  const int lane = tid & 63;
  const int wid  = tid >> 6;
  const int wr   = wid >> 2;        // 0..1 : wave row  (128 rows each)
  const int wc   = wid & 3;         // 0..3 : wave col  (64 cols each)
  const int lr   = lane & 15;
  const int lg   = lane >> 4;

  const char* Ab = (const char*)(Xb + (size_t)m0 * K_TOT);
  const char* Bb = (const char*)(Wb + (size_t)n0 * K_TOT);

  f32x4 acc[8][4];
  const f32x4 vz = {0.f, 0.f, 0.f, 0.f};
  #pragma unroll
  for (int m = 0; m < 8; ++m)
    #pragma unroll
    for (int n = 0; n < 4; ++n) acc[m][n] = vz;

  // stage one 128-row half of one matrix of tile tt (2 gloads/thread).
  // dest is wave-linear (base + lane*16); source slot pre-swizzled ^(row&7).
  #define STAGE_HALF(gb, loff, tt, h)                                         \
    {                                                                         \
      char* l = lds + (loff) + (((tt) & 1) << 15);                            \
      _Pragma("unroll")                                                       \
      for (int j = 0; j < 2; ++j) {                                           \
        int r = (h) * 128 + j * 64 + (tid >> 3);                              \
        gload_lds16((gb) + (size_t)r * (K_TOT * 2) + (size_t)(tt) * (BK * 2)  \
                        + (((tid & 7) ^ (r & 7)) << 4),                       \
                    l + r * 128 + ((tid & 7) << 4));                          \
      }                                                                       \
    }

  #define BAR()                                                               \
    { asm volatile("" ::: "memory");                                          \
      __builtin_amdgcn_s_barrier();                                           \
      asm volatile("" ::: "memory"); }

  #define LGKM0()                                                             \
    { asm volatile("s_waitcnt lgkmcnt(0)" ::: "memory");                      \
      __builtin_amdgcn_sched_barrier(0); }

  #define VMC(n)                                                              \
    { asm volatile("s_waitcnt vmcnt(" #n ")" ::: "memory");                   \
      __builtin_amdgcn_sched_barrier(0); }

  // read A quadrant: 8 frags (4 mm x 2 ks)
  #define READ_A(dst, tb, mh)                                                 \
    _Pragma("unroll")                                                         \
    for (int mm = 0; mm < 4; ++mm)                                            \
      _Pragma("unroll")                                                       \
      for (int ks = 0; ks < 2; ++ks) {                                        \
        int row = wr * 128 + (mh) * 64 + mm * 16 + lr;                        \
        dst[mm][ks] = *(const short8*)(lds + ((tb) << 15) + row * 128 +       \
                                       ((((ks << 2) | lg) ^ (row & 7)) << 4));\
      }

  // read B quadrant: 4 frags (2 nn x 2 ks)
  #define READ_B(dst, tb, nh)                                                 \
    _Pragma("unroll")                                                         \
    for (int nn = 0; nn < 2; ++nn)                                            \
      _Pragma("unroll")                                                       \
      for (int ks = 0; ks < 2; ++ks) {                                        \
        int row = wc * 64 + (nh) * 32 + nn * 16 + lr;                         \
        dst[nn][ks] = *(const short8*)(lds + 65536 + ((tb) << 15) +           \
                                       row * 128 +                            \
                                       ((((ks << 2) | lg) ^ (row & 7)) << 4));\
      }

  #define MFMA_Q(mh, nh, A, Bf)                                               \
    __builtin_amdgcn_s_setprio(1);                                            \
    _Pragma("unroll")                                                         \
    for (int ks = 0; ks < 2; ++ks)                                            \
      _Pragma("unroll")                                                       \
      for (int mm = 0; mm < 4; ++mm)                                          \
        _Pragma("unroll")                                                     \
        for (int nn = 0; nn < 2; ++nn)                                        \
          acc[(mh) * 4 + mm][(nh) * 2 + nn] =                                 \
              __builtin_amdgcn_mfma_f32_16x16x32_bf16(                        \
                  A[mm][ks], Bf[nn][ks], acc[(mh) * 4 + mm][(nh) * 2 + nn],   \
                  0, 0, 0);                                                   \
    __builtin_amdgcn_s_setprio(0);

  // prologue: A(0), B(0) fully + B(1) (deep prefetch); certify A(0)+B(0)
  STAGE_HALF(Ab, 0, 0, 0);
  STAGE_HALF(Ab, 0, 0, 1);
  STAGE_HALF(Bb, 65536, 0, 0);
  STAGE_HALF(Bb, 65536, 0, 1);
  STAGE_HALF(Bb, 65536, 1, 0);
  STAGE_HALF(Bb, 65536, 1, 1);
  VMC(4);
  BAR();

  short8 afr[4][2], bfr0[2][2], bfr1[2][2];
  READ_B(bfr0, 0, 0);   // tile 0 nh0 (normally issued by previous q3)

  for (int t = 0; t < NT; ++t) {
    const int tb = t & 1;
    // ---- q0: read A(mh0); stage Ah0(t+1) ----
    READ_A(afr, tb, 0);
    if (t + 1 < NT) STAGE_HALF(Ab, 0, t + 1, 0);
    BAR();
    LGKM0();
    MFMA_Q(0, 0, afr, bfr0);
    BAR();
    // ---- q1: read B(nh1); stage Ah1(t+1) ----
    READ_B(bfr1, tb, 1);
    if (t + 1 < NT) STAGE_HALF(Ab, 0, t + 1, 1);
    BAR();
    LGKM0();
    MFMA_Q(0, 1, afr, bfr1);
    BAR();
    // ---- q2: read A(mh1); stage Bh0(t+2) (B(t) fully consumed at q1) ----
    READ_A(afr, tb, 1);
    if (t + 2 < NT) STAGE_HALF(Bb, 65536, t + 2, 0);
    BAR();
    LGKM0();
    MFMA_Q(1, 1, afr, bfr1);
    BAR();
    // ---- q3: stage Bh1(t+2); counted-vmcnt certification of tile t+1 ----
    if (t + 2 < NT) STAGE_HALF(Bb, 65536, t + 2, 1);
    if (t < NT - 2) { VMC(4); } else { VMC(0); }
    BAR();                       // collective: tile t+1 landed for all waves
    MFMA_Q(1, 0, afr, bfr0);     // consumes old bfr0
    if (t + 1 < NT) READ_B(bfr0, tb ^ 1, 0);  // prefetch-read t+1's nh0
    BAR();
  }

  // ---- epilogue: bias + activation -> bf16 -> LDS -> coalesced stores ----
  const int chunk = n0 >> 10;                 // block-uniform (BN=256 | 1024)
  const int hbase = (n0 & (H_DIM - 1)) + wc * 64;
  unsigned short* dst = (chunk == 0) ? wsZ : (chunk == 1) ? wsF : wsO;

  char* ep = lds + wid * 16384;               // 128 rows x 64 cols bf16
  float bv[4];
  #pragma unroll
  for (int n = 0; n < 4; ++n) bv[n] = bias[n0 + wc * 64 + n * 16 + lr];

  #pragma unroll
  for (int m = 0; m < 8; ++m)
    #pragma unroll
    for (int n = 0; n < 4; ++n)
      #pragma unroll
      for (int r = 0; r < 4; ++r) {
        float y = acc[m][n][r] + bv[n];
        float v = (chunk == 0) ? tanhf_fast(y) : sigmoidf_fast(y);
        int rowl = m * 16 + lg * 4 + r;       // 0..127
        *(unsigned short*)(ep + rowl * 128 + ((n * 16 + lr) << 1)) = f2bfbits(v);
      }

  // same-wave LDS readback (compiler inserts lgkmcnt for the alias)
  #pragma unroll
  for (int it = 0; it < 16; ++it) {
    int rl = it * 8 + (lane >> 3);
    short8 v = *(const short8*)(ep + rl * 128 + ((lane & 7) << 4));
    size_t grow = (size_t)(m0 + wr * 128 + rl);
    *(short8*)((char*)dst + (grow * H_DIM + hbase) * 2 + ((lane & 7) << 4)) = v;
  }
}

// ---------- blocked scan pass 1: per-chunk (prod F, acc from 0) ----------
__global__ void scan_pass1(const __hip_bfloat16* __restrict__ F,
                           const __hip_bfloat16* __restrict__ Z,
                           float* __restrict__ chP, float* __restrict__ chA) {
  int t  = blockIdx.x * 256 + threadIdx.x;  // 0 .. NCHUNK*NCH-1
  int ch = t & (NCH - 1);
  int c  = t >> 14;
  size_t base = (size_t)c * CLEN * NCH + ch;
  float P = 1.f, A = 0.f;
  #pragma unroll 8
  for (int i = 0; i < CLEN; ++i) {
    float f = __bfloat162float(F[base + (size_t)i * NCH]);
    float z = __bfloat162float(Z[base + (size_t)i * NCH]);
    A = fmaf(f, A, (1.f - f) * z);
    P *= f;
  }
  chP[t] = P;
  chA[t] = A;
}

// ---------- mid scan: sequential over 32 chunks per channel ----------
__global__ void scan_mid(const float* __restrict__ chP, const float* __restrict__ chA,
                         const float* __restrict__ hidden,
                         float* __restrict__ Cst, float* __restrict__ outLast) {
  int ch = blockIdx.x * 256 + threadIdx.x;  // 0..16383
  float c0 = hidden[ch];
  #pragma unroll
  for (int c = 0; c < NCHUNK; ++c) {
    Cst[c * NCH + ch] = c0;
    c0 = fmaf(chP[c * NCH + ch], c0, chA[c * NCH + ch]);
  }
  outLast[ch] = c0;  // C[S-1] output (fp32)
}

// ---------- pass 2: recompute within chunk with correct start, fuse Hout ----------
__global__ void scan_pass2(const __hip_bfloat16* __restrict__ F,
                           const __hip_bfloat16* __restrict__ Z,
                           const __hip_bfloat16* __restrict__ O,
                           const float* __restrict__ Cst,
                           float* __restrict__ out) {
  int t  = blockIdx.x * 256 + threadIdx.x;
  int ch = t & (NCH - 1);
  int c  = t >> 14;
  float C = Cst[c * NCH + ch];
  size_t base = (size_t)c * CLEN * NCH + ch;
  #pragma unroll 8
  for (int i = 0; i < CLEN; ++i) {
    size_t idx = base + (size_t)i * NCH;
    float f = __bfloat162float(F[idx]);
    float z = __bfloat162float(Z[idx]);
    C = fmaf(f, C, (1.f - f) * z);
    out[idx] = __bfloat162float(O[idx]) * C;
  }
}

extern "C" void kernel_launch(void* const* d_in, const int* in_sizes, int n_in,
                              void* d_out, int out_size, void* d_ws, size_t ws_size,
                              hipStream_t stream) {
  const float* X      = (const float*)d_in[0];  // [S,B,D]
  const float* hidden = (const float*)d_in[1];  // [B,H]
  const float* W      = (const float*)d_in[2];  // [3H,D]
  const float* bias   = (const float*)d_in[3];  // [3H]
  float* out = (float*)d_out;                   // Hout [S,B,H] then C_last [1,B,H]

  char* ws = (char*)d_ws;
  __hip_bfloat16* Xb  = (__hip_bfloat16*)(ws);                 // 67,108,864
  __hip_bfloat16* Wb  = (__hip_bfloat16*)(ws + 67108864);      //  6,291,456
  unsigned short* wsZ = (unsigned short*)(ws + 73400320);      // 67,108,864 (bf16 bits)
  unsigned short* wsF = (unsigned short*)(ws + 140509184);     // 67,108,864
  unsigned short* wsO = (unsigned short*)(ws + 207618048);     // 67,108,864
  float* chP = (float*)(ws + 274726912);                       //  2,097,152
  float* chA = (float*)(ws + 276824064);                       //  2,097,152
  float* Cst = (float*)(ws + 278921216);                       //  2,097,152

  // 1) convert X and W to bf16
  cvt_kernel<<<(M_TOT * K_TOT / 4 + 255) / 256, 256, 0, stream>>>(X, (unsigned short*)Xb, M_TOT * K_TOT / 4);
  cvt_kernel<<<(N_TOT * K_TOT / 4 + 255) / 256, 256, 0, stream>>>(W, (unsigned short*)Wb, N_TOT * K_TOT / 4);

  // 2) fused GEMM + bias + activations
  gemm_act<<<NWG, 512, 0, stream>>>(Xb, Wb, bias, wsZ, wsF, wsO);

  // 3) blocked linear scan
  scan_pass1<<<(NCHUNK * NCH) / 256, 256, 0, stream>>>(
      (const __hip_bfloat16*)wsF, (const __hip_bfloat16*)wsZ, chP, chA);
  scan_mid<<<NCH / 256, 256, 0, stream>>>(chP, chA, hidden, Cst, out + (size_t)M_TOT * H_DIM);
  scan_pass2<<<(NCHUNK * NCH) / 256, 256, 0, stream>>>(
      (const __hip_bfloat16*)wsF, (const __hip_bfloat16*)wsZ,
      (const __hip_bfloat16*)wsO, Cst, out);
}

// Round 6
// 343.965 us; speedup vs baseline: 1.2444x; 1.0843x over previous
//
#include <hip/hip_runtime.h>
#include <hip/hip_bf16.h>
#include <stdint.h>

#define S_LEN 2048
#define B_SZ  16
#define D_DIM 1024
#define H_DIM 1024
#define M_TOT (S_LEN * B_SZ)      // 32768
#define N_TOT (3 * H_DIM)         // 3072
#define K_TOT D_DIM               // 1024

// ---- GEMM geometry: 256x256 tile, BK=64, 8 waves (2Mx4N), 512 threads ----
#define BM 256
#define BN 256
#define BK 64
#define NT   (K_TOT / BK)         // 16 K-tiles
#define NTN  (N_TOT / BN)         // 12
#define NWG  ((M_TOT / BM) * NTN) // 1536 (divisible by 8 -> simple XCD swizzle)

#define NCHUNK 32
#define CLEN   64                 // NCHUNK*CLEN == S_LEN
#define NCH    (B_SZ * H_DIM)     // 16384 independent channels

typedef __attribute__((ext_vector_type(8))) short short8;
typedef __attribute__((ext_vector_type(4))) float f32x4;

// ---------- helpers ----------
__device__ __forceinline__ void gload_lds16(const void* g, void* l) {
  __builtin_amdgcn_global_load_lds((__attribute__((address_space(1))) void*)g,
                                   (__attribute__((address_space(3))) void*)l,
                                   16, 0, 0);
}

__device__ __forceinline__ unsigned short f2bfbits(float x) {
  union { __hip_bfloat16 h; unsigned short u; } cv;
  cv.h = __float2bfloat16(x);
  return cv.u;
}

// cheap native sigmoid/tanh (v_exp + v_rcp); |y| <= ~40 in this problem
__device__ __forceinline__ float sig_fast(float y) {
  float e = __expf(y);
  return e * __builtin_amdgcn_rcpf(1.f + e);
}
__device__ __forceinline__ float tanh_fast(float y) {
  float e = __expf(2.f * y);
  return 2.f * (e * __builtin_amdgcn_rcpf(1.f + e)) - 1.f;
}

// ---------- fp32 -> bf16 conversion (vectorized) ----------
__global__ void cvt_kernel(const float* __restrict__ in,
                           unsigned short* __restrict__ out, int n4) {
  int i = blockIdx.x * 256 + threadIdx.x;
  if (i < n4) {
    float4 v = ((const float4*)in)[i];
    ushort4 o;
    o.x = f2bfbits(v.x); o.y = f2bfbits(v.y);
    o.z = f2bfbits(v.z); o.w = f2bfbits(v.w);
    ((ushort4*)out)[i] = o;
  }
}

// ---------- GEMM: Y = Xb * Wb^T + bias -> raw bf16 Y chunks ----------
// Activations moved to the scan kernels (they are memory-bound; VALU free).
// 4 quadrant-phases/K-tile; staggered 2-phase-deep prefetch:
//   q0: stage Ah0(t+1)   q1: stage Ah1(t+1)   q2: stage Bh0(t+2)
//   q3: stage Bh1(t+2); vmcnt(4) certifies A(t+1)+B(t+1); barrier.
// LDS: A [2 buf][256 rows][128 B] @0, B same @65536 (128 KiB).
// slot^(row&7) involution swizzle (pre-swizzled global source + read-side).
__global__ __launch_bounds__(512, 2) void gemm_act(
    const __hip_bfloat16* __restrict__ Xb,
    const __hip_bfloat16* __restrict__ Wb,
    const float* __restrict__ bias,
    unsigned short* __restrict__ wsZ,
    unsigned short* __restrict__ wsF,
    unsigned short* __restrict__ wsO) {
  __shared__ __align__(16) char lds[131072];

  int bid = blockIdx.x;
  int swz = (bid & 7) * (NWG >> 3) + (bid >> 3);   // XCD-aware, bijective
  int tm  = swz / NTN;
  int tn  = swz - tm * NTN;
  const int m0 = tm * BM;
  const int n0 = tn * BN;

  const int tid  = threadIdx.x;
  const int lane = tid & 63;
  const int wid  = tid >> 6;
  const int wr   = wid >> 2;        // 0..1 : wave row  (128 rows each)
  const int wc   = wid & 3;         // 0..3 : wave col  (64 cols each)
  const int lr   = lane & 15;
  const int lg   = lane >> 4;

  const char* Ab = (const char*)(Xb + (size_t)m0 * K_TOT);
  const char* Bb = (const char*)(Wb + (size_t)n0 * K_TOT);

  f32x4 acc[8][4];
  const f32x4 vz = {0.f, 0.f, 0.f, 0.f};
  #pragma unroll
  for (int m = 0; m < 8; ++m)
    #pragma unroll
    for (int n = 0; n < 4; ++n) acc[m][n] = vz;

  // stage one 128-row half of one matrix of tile tt (2 gloads/thread).
  // dest is wave-linear (base + lane*16); source slot pre-swizzled ^(row&7).
  #define STAGE_HALF(gb, loff, tt, h)                                         \
    {                                                                         \
      char* l = lds + (loff) + (((tt) & 1) << 15);                            \
      _Pragma("unroll")                                                       \
      for (int j = 0; j < 2; ++j) {                                           \
        int r = (h) * 128 + j * 64 + (tid >> 3);                              \
        gload_lds16((gb) + (size_t)r * (K_TOT * 2) + (size_t)(tt) * (BK * 2)  \
                        + (((tid & 7) ^ (r & 7)) << 4),                       \
                    l + r * 128 + ((tid & 7) << 4));                          \
      }                                                                       \
    }

  #define BAR()                                                               \
    { asm volatile("" ::: "memory");                                          \
      __builtin_amdgcn_s_barrier();                                           \
      asm volatile("" ::: "memory"); }

  #define LGKM0()                                                             \
    { asm volatile("s_waitcnt lgkmcnt(0)" ::: "memory");                      \
      __builtin_amdgcn_sched_barrier(0); }

  #define VMC(n)                                                              \
    { asm volatile("s_waitcnt vmcnt(" #n ")" ::: "memory");                   \
      __builtin_amdgcn_sched_barrier(0); }

  // read A quadrant: 8 frags (4 mm x 2 ks)
  #define READ_A(dst, tb, mh)                                                 \
    _Pragma("unroll")                                                         \
    for (int mm = 0; mm < 4; ++mm)                                            \
      _Pragma("unroll")                                                       \
      for (int ks = 0; ks < 2; ++ks) {                                        \
        int row = wr * 128 + (mh) * 64 + mm * 16 + lr;                        \
        dst[mm][ks] = *(const short8*)(lds + ((tb) << 15) + row * 128 +       \
                                       ((((ks << 2) | lg) ^ (row & 7)) << 4));\
      }

  // read B quadrant: 4 frags (2 nn x 2 ks)
  #define READ_B(dst, tb, nh)                                                 \
    _Pragma("unroll")                                                         \
    for (int nn = 0; nn < 2; ++nn)                                            \
      _Pragma("unroll")                                                       \
      for (int ks = 0; ks < 2; ++ks) {                                        \
        int row = wc * 64 + (nh) * 32 + nn * 16 + lr;                         \
        dst[nn][ks] = *(const short8*)(lds + 65536 + ((tb) << 15) +           \
                                       row * 128 +                            \
                                       ((((ks << 2) | lg) ^ (row & 7)) << 4));\
      }

  #define MFMA_Q(mh, nh, A, Bf)                                               \
    __builtin_amdgcn_s_setprio(1);                                            \
    _Pragma("unroll")                                                         \
    for (int ks = 0; ks < 2; ++ks)                                            \
      _Pragma("unroll")                                                       \
      for (int mm = 0; mm < 4; ++mm)                                          \
        _Pragma("unroll")                                                     \
        for (int nn = 0; nn < 2; ++nn)                                        \
          acc[(mh) * 4 + mm][(nh) * 2 + nn] =                                 \
              __builtin_amdgcn_mfma_f32_16x16x32_bf16(                        \
                  A[mm][ks], Bf[nn][ks], acc[(mh) * 4 + mm][(nh) * 2 + nn],   \
                  0, 0, 0);                                                   \
    __builtin_amdgcn_s_setprio(0);

  // prologue: A(0), B(0) fully + B(1) (deep prefetch); certify A(0)+B(0)
  STAGE_HALF(Ab, 0, 0, 0);
  STAGE_HALF(Ab, 0, 0, 1);
  STAGE_HALF(Bb, 65536, 0, 0);
  STAGE_HALF(Bb, 65536, 0, 1);
  STAGE_HALF(Bb, 65536, 1, 0);
  STAGE_HALF(Bb, 65536, 1, 1);
  VMC(4);
  BAR();

  short8 afr[4][2], bfr0[2][2], bfr1[2][2];
  READ_B(bfr0, 0, 0);   // tile 0 nh0 (normally issued by previous q3)

  for (int t = 0; t < NT; ++t) {
    const int tb = t & 1;
    // ---- q0: read A(mh0); stage Ah0(t+1) ----
    READ_A(afr, tb, 0);
    if (t + 1 < NT) STAGE_HALF(Ab, 0, t + 1, 0);
    BAR();
    LGKM0();
    MFMA_Q(0, 0, afr, bfr0);
    BAR();
    // ---- q1: read B(nh1); stage Ah1(t+1) ----
    READ_B(bfr1, tb, 1);
    if (t + 1 < NT) STAGE_HALF(Ab, 0, t + 1, 1);
    BAR();
    LGKM0();
    MFMA_Q(0, 1, afr, bfr1);
    BAR();
    // ---- q2: read A(mh1); stage Bh0(t+2) (B(t) fully consumed at q1) ----
    READ_A(afr, tb, 1);
    if (t + 2 < NT) STAGE_HALF(Bb, 65536, t + 2, 0);
    BAR();
    LGKM0();
    MFMA_Q(1, 1, afr, bfr1);
    BAR();
    // ---- q3: stage Bh1(t+2); counted-vmcnt certification of tile t+1 ----
    if (t + 2 < NT) STAGE_HALF(Bb, 65536, t + 2, 1);
    if (t < NT - 2) { VMC(4); } else { VMC(0); }
    BAR();                       // collective: tile t+1 landed for all waves
    MFMA_Q(1, 0, afr, bfr0);     // consumes old bfr0
    if (t + 1 < NT) READ_B(bfr0, tb ^ 1, 0);  // prefetch-read t+1's nh0
    BAR();
  }

  // ---- epilogue: bias only -> raw bf16 Y -> LDS -> coalesced stores ----
  const int chunk = n0 >> 10;                 // block-uniform (BN=256 | 1024)
  const int hbase = (n0 & (H_DIM - 1)) + wc * 64;
  unsigned short* dst = (chunk == 0) ? wsZ : (chunk == 1) ? wsF : wsO;

  char* ep = lds + wid * 16384;               // 128 rows x 64 cols bf16
  float bv[4];
  #pragma unroll
  for (int n = 0; n < 4; ++n) bv[n] = bias[n0 + wc * 64 + n * 16 + lr];

  #pragma unroll
  for (int m = 0; m < 8; ++m)
    #pragma unroll
    for (int n = 0; n < 4; ++n)
      #pragma unroll
      for (int r = 0; r < 4; ++r) {
        int rowl = m * 16 + lg * 4 + r;       // 0..127
        *(unsigned short*)(ep + rowl * 128 + ((n * 16 + lr) << 1)) =
            f2bfbits(acc[m][n][r] + bv[n]);
      }

  // same-wave LDS readback (compiler inserts lgkmcnt for the alias)
  #pragma unroll
  for (int it = 0; it < 16; ++it) {
    int rl = it * 8 + (lane >> 3);
    short8 v = *(const short8*)(ep + rl * 128 + ((lane & 7) << 4));
    size_t grow = (size_t)(m0 + wr * 128 + rl);
    *(short8*)((char*)dst + (grow * H_DIM + hbase) * 2 + ((lane & 7) << 4)) = v;
  }
}

// ---------- blocked scan pass 1: per-chunk (prod F, acc from 0) ----------
// Applies sigmoid/tanh to raw Y on the fly (memory-bound; VALU is free).
__global__ void scan_pass1(const __hip_bfloat16* __restrict__ F,
                           const __hip_bfloat16* __restrict__ Z,
                           float* __restrict__ chP, float* __restrict__ chA) {
  int t  = blockIdx.x * 256 + threadIdx.x;  // 0 .. NCHUNK*NCH-1
  int ch = t & (NCH - 1);
  int c  = t >> 14;
  size_t base = (size_t)c * CLEN * NCH + ch;
  float P = 1.f, A = 0.f;
  #pragma unroll 8
  for (int i = 0; i < CLEN; ++i) {
    float f = sig_fast(__bfloat162float(F[base + (size_t)i * NCH]));
    float z = tanh_fast(__bfloat162float(Z[base + (size_t)i * NCH]));
    A = fmaf(f, A, (1.f - f) * z);
    P *= f;
  }
  chP[t] = P;
  chA[t] = A;
}

// ---------- mid scan: sequential over 32 chunks per channel ----------
__global__ void scan_mid(const float* __restrict__ chP, const float* __restrict__ chA,
                         const float* __restrict__ hidden,
                         float* __restrict__ Cst, float* __restrict__ outLast) {
  int ch = blockIdx.x * 256 + threadIdx.x;  // 0..16383
  float c0 = hidden[ch];
  #pragma unroll
  for (int c = 0; c < NCHUNK; ++c) {
    Cst[c * NCH + ch] = c0;
    c0 = fmaf(chP[c * NCH + ch], c0, chA[c * NCH + ch]);
  }
  outLast[ch] = c0;  // C[S-1] output (fp32)
}

// ---------- pass 2: recompute within chunk with correct start, fuse Hout ----------
__global__ void scan_pass2(const __hip_bfloat16* __restrict__ F,
                           const __hip_bfloat16* __restrict__ Z,
                           const __hip_bfloat16* __restrict__ O,
                           const float* __restrict__ Cst,
                           float* __restrict__ out) {
  int t  = blockIdx.x * 256 + threadIdx.x;
  int ch = t & (NCH - 1);
  int c  = t >> 14;
  float C = Cst[c * NCH + ch];
  size_t base = (size_t)c * CLEN * NCH + ch;
  #pragma unroll 8
  for (int i = 0; i < CLEN; ++i) {
    size_t idx = base + (size_t)i * NCH;
    float f = sig_fast(__bfloat162float(F[idx]));
    float z = tanh_fast(__bfloat162float(Z[idx]));
    C = fmaf(f, C, (1.f - f) * z);
    out[idx] = sig_fast(__bfloat162float(O[idx])) * C;
  }
}

extern "C" void kernel_launch(void* const* d_in, const int* in_sizes, int n_in,
                              void* d_out, int out_size, void* d_ws, size_t ws_size,
                              hipStream_t stream) {
  const float* X      = (const float*)d_in[0];  // [S,B,D]
  const float* hidden = (const float*)d_in[1];  // [B,H]
  const float* W      = (const float*)d_in[2];  // [3H,D]
  const float* bias   = (const float*)d_in[3];  // [3H]
  float* out = (float*)d_out;                   // Hout [S,B,H] then C_last [1,B,H]

  char* ws = (char*)d_ws;
  __hip_bfloat16* Xb  = (__hip_bfloat16*)(ws);                 // 67,108,864
  __hip_bfloat16* Wb  = (__hip_bfloat16*)(ws + 67108864);      //  6,291,456
  unsigned short* wsZ = (unsigned short*)(ws + 73400320);      // 67,108,864 (raw Y bf16)
  unsigned short* wsF = (unsigned short*)(ws + 140509184);     // 67,108,864
  unsigned short* wsO = (unsigned short*)(ws + 207618048);     // 67,108,864
  float* chP = (float*)(ws + 274726912);                       //  2,097,152
  float* chA = (float*)(ws + 276824064);                       //  2,097,152
  float* Cst = (float*)(ws + 278921216);                       //  2,097,152

  // 1) convert X and W to bf16
  cvt_kernel<<<(M_TOT * K_TOT / 4 + 255) / 256, 256, 0, stream>>>(X, (unsigned short*)Xb, M_TOT * K_TOT / 4);
  cvt_kernel<<<(N_TOT * K_TOT / 4 + 255) / 256, 256, 0, stream>>>(W, (unsigned short*)Wb, N_TOT * K_TOT / 4);

  // 2) fused GEMM + bias (raw Y out; activations deferred to scans)
  gemm_act<<<NWG, 512, 0, stream>>>(Xb, Wb, bias, wsZ, wsF, wsO);

  // 3) blocked linear scan (activations fused here)
  scan_pass1<<<(NCHUNK * NCH) / 256, 256, 0, stream>>>(
      (const __hip_bfloat16*)wsF, (const __hip_bfloat16*)wsZ, chP, chA);
  scan_mid<<<NCH / 256, 256, 0, stream>>>(chP, chA, hidden, Cst, out + (size_t)M_TOT * H_DIM);
  scan_pass2<<<(NCHUNK * NCH) / 256, 256, 0, stream>>>(
      (const __hip_bfloat16*)wsF, (const __hip_bfloat16*)wsZ,
      (const __hip_bfloat16*)wsO, Cst, out);
}

// Round 7
// 335.491 us; speedup vs baseline: 1.2758x; 1.0253x over previous
//
#include <hip/hip_runtime.h>
#include <hip/hip_bf16.h>
#include <stdint.h>

#define S_LEN 2048
#define B_SZ  16
#define D_DIM 1024
#define H_DIM 1024
#define M_TOT (S_LEN * B_SZ)      // 32768
#define N_TOT (3 * H_DIM)         // 3072
#define K_TOT D_DIM               // 1024

// ---- GEMM geometry: 256x256 tile, BK=64, 8 waves (2Mx4N), 512 threads ----
#define BM 256
#define BN 256
#define BK 64
#define NT   (K_TOT / BK)         // 16 K-tiles
#define NTN  (N_TOT / BN)         // 12
#define NWG  ((M_TOT / BM) * NTN) // 1536 (divisible by 8 -> simple XCD swizzle)

#define NCHUNK 32
#define CLEN   64                 // NCHUNK*CLEN == S_LEN
#define NCH    (B_SZ * H_DIM)     // 16384 independent channels

typedef __attribute__((ext_vector_type(8))) short short8;
typedef __attribute__((ext_vector_type(4))) float f32x4;

// ---------- helpers ----------
__device__ __forceinline__ void gload_lds16(const void* g, void* l) {
  __builtin_amdgcn_global_load_lds((__attribute__((address_space(1))) void*)g,
                                   (__attribute__((address_space(3))) void*)l,
                                   16, 0, 0);
}

__device__ __forceinline__ unsigned short f2bfbits(float x) {
  union { __hip_bfloat16 h; unsigned short u; } cv;
  cv.h = __float2bfloat16(x);
  return cv.u;
}

// cheap native sigmoid/tanh (v_exp + v_rcp); |y| <= ~40 in this problem
__device__ __forceinline__ float sig_fast(float y) {
  float e = __expf(y);
  return e * __builtin_amdgcn_rcpf(1.f + e);
}
__device__ __forceinline__ float tanh_fast(float y) {
  float e = __expf(2.f * y);
  return 2.f * (e * __builtin_amdgcn_rcpf(1.f + e)) - 1.f;
}

// ---------- fp32 -> bf16 conversion (vectorized) ----------
__global__ void cvt_kernel(const float* __restrict__ in,
                           unsigned short* __restrict__ out, int n4) {
  int i = blockIdx.x * 256 + threadIdx.x;
  if (i < n4) {
    float4 v = ((const float4*)in)[i];
    ushort4 o;
    o.x = f2bfbits(v.x); o.y = f2bfbits(v.y);
    o.z = f2bfbits(v.z); o.w = f2bfbits(v.w);
    ((ushort4*)out)[i] = o;
  }
}

// ---------- GEMM: Y = Xb * Wb^T + bias -> raw bf16 Y chunks ----------
// 2 barriers per K-tile (free-running waves inside a tile):
//   [reads of tile t + stage A(t+1) + 64 MFMA]  BAR#1 (B(t) regs consumed)
//   [stage Bh(t+2) into B-slot t&1]  vmcnt(4)  BAR#2 (certify t+1)  [read bfr0(t+1)]
// Counted vmcnt(4): leaves exactly B(t+2)'s 4 loads in flight; A(t+1)+B(t+1)
// certified. Compiler's fine-grained lgkmcnt orders ds_read->MFMA per wave.
// LDS: A [2 buf][256 rows][128 B] @0, B same @65536 (128 KiB).
// slot^(row&7) involution swizzle (pre-swizzled global source + read-side).
__global__ __launch_bounds__(512, 2) void gemm_act(
    const __hip_bfloat16* __restrict__ Xb,
    const __hip_bfloat16* __restrict__ Wb,
    const float* __restrict__ bias,
    unsigned short* __restrict__ wsZ,
    unsigned short* __restrict__ wsF,
    unsigned short* __restrict__ wsO) {
  __shared__ __align__(16) char lds[131072];

  int bid = blockIdx.x;
  int swz = (bid & 7) * (NWG >> 3) + (bid >> 3);   // XCD-aware, bijective
  int tm  = swz / NTN;
  int tn  = swz - tm * NTN;
  const int m0 = tm * BM;
  const int n0 = tn * BN;

  const int tid  = threadIdx.x;
  const int lane = tid & 63;
  const int wid  = tid >> 6;
  const int wr   = wid >> 2;        // 0..1 : wave row  (128 rows each)
  const int wc   = wid & 3;         // 0..3 : wave col  (64 cols each)
  const int lr   = lane & 15;
  const int lg   = lane >> 4;

  const char* Ab = (const char*)(Xb + (size_t)m0 * K_TOT);
  const char* Bb = (const char*)(Wb + (size_t)n0 * K_TOT);

  f32x4 acc[8][4];
  const f32x4 vz = {0.f, 0.f, 0.f, 0.f};
  #pragma unroll
  for (int m = 0; m < 8; ++m)
    #pragma unroll
    for (int n = 0; n < 4; ++n) acc[m][n] = vz;

  // stage one 128-row half of one matrix of tile tt (2 gloads/thread).
  // dest is wave-linear (base + lane*16); source slot pre-swizzled ^(row&7).
  #define STAGE_HALF(gb, loff, tt, h)                                         \
    {                                                                         \
      char* l = lds + (loff) + (((tt) & 1) << 15);                            \
      _Pragma("unroll")                                                       \
      for (int j = 0; j < 2; ++j) {                                           \
        int r = (h) * 128 + j * 64 + (tid >> 3);                              \
        gload_lds16((gb) + (size_t)r * (K_TOT * 2) + (size_t)(tt) * (BK * 2)  \
                        + (((tid & 7) ^ (r & 7)) << 4),                       \
                    l + r * 128 + ((tid & 7) << 4));                          \
      }                                                                       \
    }

  #define BAR()                                                               \
    { asm volatile("" ::: "memory");                                          \
      __builtin_amdgcn_s_barrier();                                           \
      asm volatile("" ::: "memory"); }

  #define VMC(n)                                                              \
    { asm volatile("s_waitcnt vmcnt(" #n ")" ::: "memory");                   \
      __builtin_amdgcn_sched_barrier(0); }

  // read A quadrant: 8 frags (4 mm x 2 ks)
  #define READ_A(dst, tb, mh)                                                 \
    _Pragma("unroll")                                                         \
    for (int mm = 0; mm < 4; ++mm)                                            \
      _Pragma("unroll")                                                       \
      for (int ks = 0; ks < 2; ++ks) {                                        \
        int row = wr * 128 + (mh) * 64 + mm * 16 + lr;                        \
        dst[mm][ks] = *(const short8*)(lds + ((tb) << 15) + row * 128 +       \
                                       ((((ks << 2) | lg) ^ (row & 7)) << 4));\
      }

  // read B quadrant: 4 frags (2 nn x 2 ks)
  #define READ_B(dst, tb, nh)                                                 \
    _Pragma("unroll")                                                         \
    for (int nn = 0; nn < 2; ++nn)                                            \
      _Pragma("unroll")                                                       \
      for (int ks = 0; ks < 2; ++ks) {                                        \
        int row = wc * 64 + (nh) * 32 + nn * 16 + lr;                         \
        dst[nn][ks] = *(const short8*)(lds + 65536 + ((tb) << 15) +           \
                                       row * 128 +                            \
                                       ((((ks << 2) | lg) ^ (row & 7)) << 4));\
      }

  #define MFMA_Q(mh, nh, A, Bf)                                               \
    __builtin_amdgcn_s_setprio(1);                                            \
    _Pragma("unroll")                                                         \
    for (int ks = 0; ks < 2; ++ks)                                            \
      _Pragma("unroll")                                                       \
      for (int mm = 0; mm < 4; ++mm)                                          \
        _Pragma("unroll")                                                     \
        for (int nn = 0; nn < 2; ++nn)                                        \
          acc[(mh) * 4 + mm][(nh) * 2 + nn] =                                 \
              __builtin_amdgcn_mfma_f32_16x16x32_bf16(                        \
                  A[mm][ks], Bf[nn][ks], acc[(mh) * 4 + mm][(nh) * 2 + nn],   \
                  0, 0, 0);                                                   \
    __builtin_amdgcn_s_setprio(0);

  // prologue: A(0), B(0) fully + B(1) (deep prefetch); certify A(0)+B(0)
  STAGE_HALF(Ab, 0, 0, 0);
  STAGE_HALF(Ab, 0, 0, 1);
  STAGE_HALF(Bb, 65536, 0, 0);
  STAGE_HALF(Bb, 65536, 0, 1);
  STAGE_HALF(Bb, 65536, 1, 0);
  STAGE_HALF(Bb, 65536, 1, 1);
  VMC(4);
  BAR();

  short8 afr[4][2], bfr0[2][2], bfr1[2][2];
  READ_B(bfr0, 0, 0);   // tile 0 nh0 (normally issued by previous tile's tail)

  for (int t = 0; t < NT; ++t) {
    const int tb = t & 1;
    // ---- tile-t compute: reads up front, A(t+1) staged, 4 MFMA quadrants ----
    READ_A(afr, tb, 0);          // 8 reads (mh0)
    READ_B(bfr1, tb, 1);         // 4 reads (nh1)
    if (t + 1 < NT) {
      STAGE_HALF(Ab, 0, t + 1, 0);
      STAGE_HALF(Ab, 0, t + 1, 1);
    }
    MFMA_Q(0, 0, afr, bfr0);     // compiler inserts fine lgkmcnt for afr/bfr
    MFMA_Q(0, 1, afr, bfr1);
    READ_A(afr, tb, 1);          // 8 reads (mh1); WAR on afr resolves at issue
    MFMA_Q(1, 1, afr, bfr1);
    MFMA_Q(1, 0, afr, bfr0);     // last consumption of B(t) registers
    BAR();                       // all waves' tile-t LDS reads complete
    // ---- stage B(t+2) into B-slot t&1 (now dead); certify tile t+1 ----
    if (t + 2 < NT) {
      STAGE_HALF(Bb, 65536, t + 2, 0);
      STAGE_HALF(Bb, 65536, t + 2, 1);
    }
    if (t < NT - 2) { VMC(4); } else { VMC(0); }
    BAR();                       // collective: tile t+1 landed for all waves
    if (t + 1 < NT) READ_B(bfr0, tb ^ 1, 0);  // prefetch-read t+1's nh0
  }

  // ---- epilogue: bias only -> raw bf16 Y -> LDS -> coalesced stores ----
  const int chunk = n0 >> 10;                 // block-uniform (BN=256 | 1024)
  const int hbase = (n0 & (H_DIM - 1)) + wc * 64;
  unsigned short* dst = (chunk == 0) ? wsZ : (chunk == 1) ? wsF : wsO;

  char* ep = lds + wid * 16384;               // 128 rows x 64 cols bf16
  float bv[4];
  #pragma unroll
  for (int n = 0; n < 4; ++n) bv[n] = bias[n0 + wc * 64 + n * 16 + lr];

  #pragma unroll
  for (int m = 0; m < 8; ++m)
    #pragma unroll
    for (int n = 0; n < 4; ++n)
      #pragma unroll
      for (int r = 0; r < 4; ++r) {
        int rowl = m * 16 + lg * 4 + r;       // 0..127
        *(unsigned short*)(ep + rowl * 128 + ((n * 16 + lr) << 1)) =
            f2bfbits(acc[m][n][r] + bv[n]);
      }

  // same-wave LDS readback (compiler inserts lgkmcnt for the alias)
  #pragma unroll
  for (int it = 0; it < 16; ++it) {
    int rl = it * 8 + (lane >> 3);
    short8 v = *(const short8*)(ep + rl * 128 + ((lane & 7) << 4));
    size_t grow = (size_t)(m0 + wr * 128 + rl);
    *(short8*)((char*)dst + (grow * H_DIM + hbase) * 2 + ((lane & 7) << 4)) = v;
  }
}

// ---------- blocked scan pass 1: per-chunk (prod F, acc from 0) ----------
// Applies sigmoid/tanh to raw Y on the fly (memory-bound; VALU is free).
__global__ void scan_pass1(const __hip_bfloat16* __restrict__ F,
                           const __hip_bfloat16* __restrict__ Z,
                           float* __restrict__ chP, float* __restrict__ chA) {
  int t  = blockIdx.x * 256 + threadIdx.x;  // 0 .. NCHUNK*NCH-1
  int ch = t & (NCH - 1);
  int c  = t >> 14;
  size_t base = (size_t)c * CLEN * NCH + ch;
  float P = 1.f, A = 0.f;
  #pragma unroll 8
  for (int i = 0; i < CLEN; ++i) {
    float f = sig_fast(__bfloat162float(F[base + (size_t)i * NCH]));
    float z = tanh_fast(__bfloat162float(Z[base + (size_t)i * NCH]));
    A = fmaf(f, A, (1.f - f) * z);
    P *= f;
  }
  chP[t] = P;
  chA[t] = A;
}

// ---------- mid scan: sequential over 32 chunks per channel ----------
__global__ void scan_mid(const float* __restrict__ chP, const float* __restrict__ chA,
                         const float* __restrict__ hidden,
                         float* __restrict__ Cst, float* __restrict__ outLast) {
  int ch = blockIdx.x * 256 + threadIdx.x;  // 0..16383
  float c0 = hidden[ch];
  #pragma unroll
  for (int c = 0; c < NCHUNK; ++c) {
    Cst[c * NCH + ch] = c0;
    c0 = fmaf(chP[c * NCH + ch], c0, chA[c * NCH + ch]);
  }
  outLast[ch] = c0;  // C[S-1] output (fp32)
}

// ---------- pass 2: recompute within chunk with correct start, fuse Hout ----------
__global__ void scan_pass2(const __hip_bfloat16* __restrict__ F,
                           const __hip_bfloat16* __restrict__ Z,
                           const __hip_bfloat16* __restrict__ O,
                           const float* __restrict__ Cst,
                           float* __restrict__ out) {
  int t  = blockIdx.x * 256 + threadIdx.x;
  int ch = t & (NCH - 1);
  int c  = t >> 14;
  float C = Cst[c * NCH + ch];
  size_t base = (size_t)c * CLEN * NCH + ch;
  #pragma unroll 8
  for (int i = 0; i < CLEN; ++i) {
    size_t idx = base + (size_t)i * NCH;
    float f = sig_fast(__bfloat162float(F[idx]));
    float z = tanh_fast(__bfloat162float(Z[idx]));
    C = fmaf(f, C, (1.f - f) * z);
    out[idx] = sig_fast(__bfloat162float(O[idx])) * C;
  }
}

extern "C" void kernel_launch(void* const* d_in, const int* in_sizes, int n_in,
                              void* d_out, int out_size, void* d_ws, size_t ws_size,
                              hipStream_t stream) {
  const float* X      = (const float*)d_in[0];  // [S,B,D]
  const float* hidden = (const float*)d_in[1];  // [B,H]
  const float* W      = (const float*)d_in[2];  // [3H,D]
  const float* bias   = (const float*)d_in[3];  // [3H]
  float* out = (float*)d_out;                   // Hout [S,B,H] then C_last [1,B,H]

  char* ws = (char*)d_ws;
  __hip_bfloat16* Xb  = (__hip_bfloat16*)(ws);                 // 67,108,864
  __hip_bfloat16* Wb  = (__hip_bfloat16*)(ws + 67108864);      //  6,291,456
  unsigned short* wsZ = (unsigned short*)(ws + 73400320);      // 67,108,864 (raw Y bf16)
  unsigned short* wsF = (unsigned short*)(ws + 140509184);     // 67,108,864
  unsigned short* wsO = (unsigned short*)(ws + 207618048);     // 67,108,864
  float* chP = (float*)(ws + 274726912);                       //  2,097,152
  float* chA = (float*)(ws + 276824064);                       //  2,097,152
  float* Cst = (float*)(ws + 278921216);                       //  2,097,152

  // 1) convert X and W to bf16
  cvt_kernel<<<(M_TOT * K_TOT / 4 + 255) / 256, 256, 0, stream>>>(X, (unsigned short*)Xb, M_TOT * K_TOT / 4);
  cvt_kernel<<<(N_TOT * K_TOT / 4 + 255) / 256, 256, 0, stream>>>(W, (unsigned short*)Wb, N_TOT * K_TOT / 4);

  // 2) fused GEMM + bias (raw Y out; activations deferred to scans)
  gemm_act<<<NWG, 512, 0, stream>>>(Xb, Wb, bias, wsZ, wsF, wsO);

  // 3) blocked linear scan (activations fused here)
  scan_pass1<<<(NCHUNK * NCH) / 256, 256, 0, stream>>>(
      (const __hip_bfloat16*)wsF, (const __hip_bfloat16*)wsZ, chP, chA);
  scan_mid<<<NCH / 256, 256, 0, stream>>>(chP, chA, hidden, Cst, out + (size_t)M_TOT * H_DIM);
  scan_pass2<<<(NCHUNK * NCH) / 256, 256, 0, stream>>>(
      (const __hip_bfloat16*)wsF, (const __hip_bfloat16*)wsZ,
      (const __hip_bfloat16*)wsO, Cst, out);
}